// Round 1
// 273.770 us; speedup vs baseline: 2.2317x; 2.2317x over previous
//
#include <hip/hip_runtime.h>

#define NCOMM 512
#define DIM   128
#define ALPHA 0.25f
#define PEPS  1e-6f
#define BIGF  1e30f

typedef __attribute__((ext_vector_type(8))) short bf16x8;
typedef __attribute__((ext_vector_type(4))) float f32x4;

__device__ __forceinline__ unsigned short bf16_rn(float v) {
    unsigned u = __float_as_uint(v);
    u += 0x7FFFu + ((u >> 16) & 1u);
    return (unsigned short)(u >> 16);
}
__device__ __forceinline__ float bf16_f(unsigned short h) {
    return __uint_as_float((unsigned)h << 16);
}

// ---------------- small prep kernels ----------------

__global__ void k_inv(const int* __restrict__ cbl, int* __restrict__ inv, int N) {
    int i = blockIdx.x * 256 + threadIdx.x;
    if (i < N) inv[cbl[i]] = i;   // perm is a permutation: direct store == scatter-add on zeros
}

__global__ void k_comm(const int* __restrict__ cbl, const int* __restrict__ inv,
                       int* __restrict__ comm, int* __restrict__ idx0,
                       int* __restrict__ counts, int N) {
    int j = blockIdx.x * 256 + threadIdx.x;
    if (j < N) {
        int ij = inv[j];
        int c  = cbl[N + ij];
        comm[j] = c;
        idx0[j] = cbl[ij];
        atomicAdd(&counts[c], 1);
    }
}

__global__ void k_scan(const int* __restrict__ counts, int* __restrict__ offsets,
                       int* __restrict__ cursor, float* __restrict__ countf) {
    __shared__ int sc[NCOMM];
    int t = threadIdx.x;
    int v0 = counts[t];
    sc[t] = v0;
    __syncthreads();
    for (int off = 1; off < NCOMM; off <<= 1) {
        int v = (t >= off) ? sc[t - off] : 0;
        __syncthreads();
        sc[t] += v;
        __syncthreads();
    }
    int excl = sc[t] - v0;
    offsets[t] = excl;
    cursor[t]  = excl;
    countf[t]  = (float)v0;
}

__global__ void k_sort(const int* __restrict__ comm, int* __restrict__ cursor,
                       int* __restrict__ sorted, int N) {
    int j = blockIdx.x * 256 + threadIdx.x;
    if (j < N) {
        int p = atomicAdd(&cursor[comm[j]], 1);
        sorted[p] = j;
    }
}

// ---------------- per-community stats: single pass sum+sumsq ----------------
// var = (sumsq - cnt*m^2)/(cnt-1): benign cancellation here (x~N(0,1), rel err ~1e-6)

__global__ void __launch_bounds__(256) k_stats(
        const float* __restrict__ NF, const int* __restrict__ idx0,
        const int* __restrict__ sorted, const int* __restrict__ offsets,
        const int* __restrict__ counts,
        float* __restrict__ comm_sum,
        unsigned short* __restrict__ CMh, unsigned short* __restrict__ CMl,
        float* __restrict__ c2, float* __restrict__ accum) {
    __shared__ float shs[128], shq[128];
    __shared__ float rs2[2], rq2[2];
    int c = blockIdx.x;
    int t = threadIdx.x;
    int d = t & 127, half = t >> 7;
    int cnt = counts[c], base = offsets[c];
    float s = 0.f, q = 0.f;
    int i = half;
    for (; i + 6 < cnt; i += 8) {
        int a0 = idx0[sorted[base + i]];
        int a1 = idx0[sorted[base + i + 2]];
        int a2 = idx0[sorted[base + i + 4]];
        int a3 = idx0[sorted[base + i + 6]];
        float v0 = NF[(size_t)a0 * DIM + d];
        float v1 = NF[(size_t)a1 * DIM + d];
        float v2 = NF[(size_t)a2 * DIM + d];
        float v3 = NF[(size_t)a3 * DIM + d];
        s += v0; q = fmaf(v0, v0, q);
        s += v1; q = fmaf(v1, v1, q);
        s += v2; q = fmaf(v2, v2, q);
        s += v3; q = fmaf(v3, v3, q);
    }
    for (; i < cnt; i += 2) {
        float v = NF[(size_t)idx0[sorted[base + i]] * DIM + d];
        s += v; q = fmaf(v, v, q);
    }
    if (half) { shs[d] = s; shq[d] = q; }
    __syncthreads();
    if (!half) {
        s += shs[d]; q += shq[d];
        float cf = (float)cnt;
        comm_sum[c * DIM + d] = s;
        float m = (cnt > 0) ? s / cf : 0.f;
        unsigned short h = bf16_rn(m);
        CMh[c * DIM + d] = h;
        CMl[c * DIM + d] = bf16_rn(m - bf16_f(h));
        float varn = fmaxf(fmaf(-cf * m, m, q), 0.f);
        float stdv = sqrtf(varn / fmaxf(cf - 1.f, 1.f));
        float e = stdv - 1.f; e = e * e;
        float mm = m * m;
        #pragma unroll
        for (int msk = 1; msk < 64; msk <<= 1) {
            mm += __shfl_xor(mm, msk);
            e  += __shfl_xor(e, msk);
        }
        if ((d & 63) == 0) { rs2[d >> 6] = mm; rq2[d >> 6] = e; }
    }
    __syncthreads();
    if (t == 0) {
        c2[c] = rs2[0] + rs2[1];
        atomicAdd(&accum[2], rq2[0] + rq2[1]);
    }
}

// ---------------- heavy kernel: MFMA distances + triplet terms ----------------
// 128 nodes/block, 4 waves x 32-row tiles, all 512 comms per block.
// bf16 hi/lo split (3 MFMAs) ~= fp32 accuracy. A frags from global fp32 (converted
// in-register, held for whole kernel); B frags from pre-split bf16 arrays (L2-hot),
// double-buffered in registers. No LDS staging for the GEMM at all.

__global__ void __launch_bounds__(256, 2) k_main(
        const float* __restrict__ NF,
        const unsigned short* __restrict__ CMh,
        const unsigned short* __restrict__ CMl,
        const float* __restrict__ comm_sum,
        const float* __restrict__ c2g,
        const float* __restrict__ countf,
        const int* __restrict__ comm,
        const int* __restrict__ idx0,
        float* __restrict__ accum, int N) {
    __shared__ float c2s[NCOMM];
    __shared__ int   comms[128];
    __shared__ float x2s[128];
    __shared__ float sums[128], mins[128], owns[128];
    __shared__ float red[8];

    int tid = threadIdx.x;
    int w  = tid >> 6;
    int l  = tid & 63;
    int lr = l & 15;      // A row within 16-frag / B (comm) col
    int lk = l >> 4;      // k-group
    int n0 = blockIdx.x * 128;

    c2s[tid]       = c2g[tid];
    c2s[tid + 256] = c2g[tid + 256];
    if (tid < 128) {
        int gn = n0 + tid;
        comms[tid] = (gn < N) ? comm[gn] : -1;
    }

    // ---- A fragments (rows w*32 + mf*16 + lr, dims lk*8.. per k-step) + exact fp32 x2
    bf16x8 ah[2][4], al[2][4];
    float p2[2] = {0.f, 0.f};
    #pragma unroll
    for (int mf = 0; mf < 2; ++mf) {
        int n = n0 + w * 32 + mf * 16 + lr;
        const float4* src = (const float4*)NF + (size_t)n * 32 + lk * 2;
        #pragma unroll
        for (int ks = 0; ks < 4; ++ks) {
            float4 v0 = make_float4(0.f, 0.f, 0.f, 0.f), v1 = v0;
            if (n < N) { v0 = src[ks * 8]; v1 = src[ks * 8 + 1]; }
            float fr[8] = {v0.x, v0.y, v0.z, v0.w, v1.x, v1.y, v1.z, v1.w};
            bf16x8 hh, ll;
            #pragma unroll
            for (int t = 0; t < 8; ++t) {
                unsigned short h = bf16_rn(fr[t]);
                hh[t] = (short)h;
                ll[t] = (short)bf16_rn(fr[t] - bf16_f(h));
                p2[mf] = fmaf(fr[t], fr[t], p2[mf]);
            }
            ah[mf][ks] = hh; al[mf][ks] = ll;
        }
        p2[mf] += __shfl_xor(p2[mf], 16);
        p2[mf] += __shfl_xor(p2[mf], 32);
        if (lk == 0) x2s[w * 32 + mf * 16 + lr] = p2[mf];
    }
    __syncthreads();

    // per-lane per-row state (C layout: row = lk*4 + j, col = lr)
    float x2v[2][4], sumv[2][4], minv[2][4], ownv[2][4];
    int cnv[2][4];
    #pragma unroll
    for (int mf = 0; mf < 2; ++mf)
        #pragma unroll
        for (int j = 0; j < 4; ++j) {
            int idx = w * 32 + mf * 16 + lk * 4 + j;
            x2v[mf][j] = x2s[idx];
            cnv[mf][j] = comms[idx];
            sumv[mf][j] = 0.f; minv[mf][j] = BIGF; ownv[mf][j] = 0.f;
        }

    const bf16x8* BH = (const bf16x8*)CMh;
    const bf16x8* BL = (const bf16x8*)CMl;
    bf16x8 bhA[4], blA[4], bhB[4], blB[4];

    auto pref = [&](bf16x8* dh, bf16x8* dl, int tt) {
        size_t base = (size_t)(tt * 16 + lr) * 16 + lk;
        #pragma unroll
        for (int ks = 0; ks < 4; ++ks) {
            dh[ks] = BH[base + ks * 4];
            dl[ks] = BL[base + ks * 4];
        }
    };
    auto comp = [&](const bf16x8* bh, const bf16x8* bl, int tt) {
        int ccol = tt * 16 + lr;
        f32x4 a0e = {0.f, 0.f, 0.f, 0.f}, a0o = a0e, a1e = a0e, a1o = a0e;
        #pragma unroll
        for (int ks = 0; ks < 4; ks += 2) {
            a0e = __builtin_amdgcn_mfma_f32_16x16x32_bf16(ah[0][ks],   bh[ks],   a0e, 0, 0, 0);
            a1e = __builtin_amdgcn_mfma_f32_16x16x32_bf16(ah[1][ks],   bh[ks],   a1e, 0, 0, 0);
            a0o = __builtin_amdgcn_mfma_f32_16x16x32_bf16(ah[0][ks+1], bh[ks+1], a0o, 0, 0, 0);
            a1o = __builtin_amdgcn_mfma_f32_16x16x32_bf16(ah[1][ks+1], bh[ks+1], a1o, 0, 0, 0);
            a0e = __builtin_amdgcn_mfma_f32_16x16x32_bf16(al[0][ks],   bh[ks],   a0e, 0, 0, 0);
            a1e = __builtin_amdgcn_mfma_f32_16x16x32_bf16(al[1][ks],   bh[ks],   a1e, 0, 0, 0);
            a0o = __builtin_amdgcn_mfma_f32_16x16x32_bf16(al[0][ks+1], bh[ks+1], a0o, 0, 0, 0);
            a1o = __builtin_amdgcn_mfma_f32_16x16x32_bf16(al[1][ks+1], bh[ks+1], a1o, 0, 0, 0);
            a0e = __builtin_amdgcn_mfma_f32_16x16x32_bf16(ah[0][ks],   bl[ks],   a0e, 0, 0, 0);
            a1e = __builtin_amdgcn_mfma_f32_16x16x32_bf16(ah[1][ks],   bl[ks],   a1e, 0, 0, 0);
            a0o = __builtin_amdgcn_mfma_f32_16x16x32_bf16(ah[0][ks+1], bl[ks+1], a0o, 0, 0, 0);
            a1o = __builtin_amdgcn_mfma_f32_16x16x32_bf16(ah[1][ks+1], bl[ks+1], a1o, 0, 0, 0);
        }
        f32x4 acc0 = a0e + a0o;
        f32x4 acc1 = a1e + a1o;
        float c2v = c2s[ccol];
        #pragma unroll
        for (int j = 0; j < 4; ++j) {
            float d2a = fmaf(-2.f, acc0[j], x2v[0][j] + c2v);
            float da  = sqrtf(fmaxf(d2a, 0.f));
            sumv[0][j] += da;
            bool oa = (cnv[0][j] == ccol);
            ownv[0][j] = oa ? da : ownv[0][j];
            minv[0][j] = oa ? minv[0][j] : fminf(minv[0][j], da);
            float d2b = fmaf(-2.f, acc1[j], x2v[1][j] + c2v);
            float db  = sqrtf(fmaxf(d2b, 0.f));
            sumv[1][j] += db;
            bool ob = (cnv[1][j] == ccol);
            ownv[1][j] = ob ? db : ownv[1][j];
            minv[1][j] = ob ? minv[1][j] : fminf(minv[1][j], db);
        }
    };

    pref(bhA, blA, 0);
    for (int t = 0; t < 32; t += 2) {
        pref(bhB, blB, t + 1);
        comp(bhA, blA, t);
        pref(bhA, blA, (t + 2 < 32) ? t + 2 : 31);
        comp(bhB, blB, t + 1);
    }

    // reduce sum/min/own across the 16 lanes (lr) sharing each node row
    #pragma unroll
    for (int mf = 0; mf < 2; ++mf)
        #pragma unroll
        for (int j = 0; j < 4; ++j) {
            float sv = sumv[mf][j], mv = minv[mf][j], ov = ownv[mf][j];
            #pragma unroll
            for (int msk = 1; msk < 16; msk <<= 1) {
                sv += __shfl_xor(sv, msk);
                mv = fminf(mv, __shfl_xor(mv, msk));
                ov += __shfl_xor(ov, msk);
            }
            if (lr == 0) {
                int idx = w * 32 + mf * 16 + lk * 4 + j;
                sums[idx] = sv; mins[idx] = mv; owns[idx] = ov;
            }
        }
    __syncthreads();

    // LOO positive distance + triplet terms (2 threads per node)
    float tmean = 0.f, tminv = 0.f;
    {
        int ln = tid >> 1, half = tid & 1;
        int n = n0 + ln;
        if (n < N) {
            int cnode = comms[ln];
            float cf  = countf[cnode];
            float cm1 = fmaxf(cf - 1.f, 1.f);
            float rs  = 1.f / cm1;
            bool single = (cf == 1.f);
            const float4* srow = (const float4*)(NF + (size_t)idx0[n] * DIM) + half * 16;
            const float4* csum = (const float4*)(comm_sum + (size_t)cnode * DIM) + half * 16;
            float q = 0.f;
            #pragma unroll
            for (int m = 0; m < 16; ++m) {
                float4 sv = srow[m];
                float4 cs = csum[m];
                float4 xm = single ? make_float4(0.f, 0.f, 0.f, 0.f) : sv;
                float lx = (cs.x - xm.x) * rs - sv.x + PEPS;
                float ly = (cs.y - xm.y) * rs - sv.y + PEPS;
                float lz = (cs.z - xm.z) * rs - sv.z + PEPS;
                float lw = (cs.w - xm.w) * rs - sv.w + PEPS;
                q = fmaf(lx, lx, fmaf(ly, ly, fmaf(lz, lz, fmaf(lw, lw, q))));
            }
            q += __shfl_xor(q, 1);
            if (half == 0) {
                float pos = sqrtf(q);
                float own = owns[ln];
                float mean_neg = (sums[ln] - own) * (1.f / (float)(NCOMM - 1));
                tmean = fmaxf(pos - mean_neg + ALPHA, 0.f);
                tminv = fmaxf(pos - mins[ln] + ALPHA, 0.f);
            }
        }
    }
    // block reduction of triplet sums
    #pragma unroll
    for (int msk = 1; msk < 64; msk <<= 1) {
        tmean += __shfl_xor(tmean, msk);
        tminv += __shfl_xor(tminv, msk);
    }
    if ((tid & 63) == 0) { red[w * 2] = tmean; red[w * 2 + 1] = tminv; }
    __syncthreads();
    if (tid == 0) {
        atomicAdd(&accum[0], red[0] + red[2] + red[4] + red[6]);
        atomicAdd(&accum[1], red[1] + red[3] + red[5] + red[7]);
    }
}

__global__ void k_final(const float* __restrict__ accum, float* __restrict__ out, int N) {
    if (threadIdx.x == 0) {
        out[0] = accum[0] / (float)N;
        out[1] = accum[1] / (float)N;
        out[2] = accum[2] / (float)(NCOMM * DIM);
    }
}

// ---------------- launch ----------------

extern "C" void kernel_launch(void* const* d_in, const int* in_sizes, int n_in,
                              void* d_out, int out_size, void* d_ws, size_t ws_size,
                              hipStream_t stream) {
    const float* NF  = (const float*)d_in[0];
    const int*   CBL = (const int*)d_in[1];
    int N = in_sizes[1] / 2;
    if (N <= 0) return;

    char* ws = (char*)d_ws;
    float* accum   = (float*)ws;                    // 16 B
    int*   counts  = (int*)(ws + 16);               // 2048
    int*   cursor  = (int*)(ws + 16 + 2048);
    int*   offsets = (int*)(ws + 16 + 2 * 2048);
    float* countf  = (float*)(ws + 16 + 3 * 2048);
    float* c2      = (float*)(ws + 16 + 4 * 2048);
    char* p = ws + 16 + 5 * 2048;
    int* inv    = (int*)p; p += (size_t)N * 4;
    int* comm   = (int*)p; p += (size_t)N * 4;
    int* idx0   = (int*)p; p += (size_t)N * 4;
    int* sorted = (int*)p; p += (size_t)N * 4;
    float* comm_sum = (float*)p; p += (size_t)NCOMM * DIM * 4;
    unsigned short* CMh = (unsigned short*)p; p += (size_t)NCOMM * DIM * 2;
    unsigned short* CMl = (unsigned short*)p;

    hipMemsetAsync(d_ws, 0, 16 + 2048, stream);     // accum + counts

    int nb = (N + 255) / 256;
    k_inv <<<nb, 256, 0, stream>>>(CBL, inv, N);
    k_comm<<<nb, 256, 0, stream>>>(CBL, inv, comm, idx0, counts, N);
    k_scan<<<1, NCOMM, 0, stream>>>(counts, offsets, cursor, countf);
    k_sort<<<nb, 256, 0, stream>>>(comm, cursor, sorted, N);
    k_stats<<<NCOMM, 256, 0, stream>>>(NF, idx0, sorted, offsets, counts,
                                       comm_sum, CMh, CMl, c2, accum);
    int mb = (N + 127) / 128;
    k_main<<<mb, 256, 0, stream>>>(NF, CMh, CMl, comm_sum, c2, countf,
                                   comm, idx0, accum, N);
    k_final<<<1, 64, 0, stream>>>(accum, (float*)d_out, N);
}

// Round 2
// 167.586 us; speedup vs baseline: 3.6458x; 1.6336x over previous
//
#include <hip/hip_runtime.h>

#define NCOMM 512
#define DIM   128
#define ALPHA 0.25f
#define PEPS  1e-6f
#define BIGF  1e30f

typedef __attribute__((ext_vector_type(8))) short bf16x8;
typedef __attribute__((ext_vector_type(4))) float f32x4;

__device__ __forceinline__ unsigned short bf16_rn(float v) {
    unsigned u = __float_as_uint(v);
    u += 0x7FFFu + ((u >> 16) & 1u);
    return (unsigned short)(u >> 16);
}
__device__ __forceinline__ float bf16_f(unsigned short h) {
    return __uint_as_float((unsigned)h << 16);
}

#define GLOAD_LDS16(g, l) __builtin_amdgcn_global_load_lds( \
    (const __attribute__((address_space(1))) void*)(g), \
    (__attribute__((address_space(3))) void*)(l), 16, 0, 0)

// ---------------- small prep kernels ----------------

__global__ void k_inv(const int* __restrict__ cbl, int* __restrict__ inv, int N) {
    int i = blockIdx.x * 256 + threadIdx.x;
    if (i < N) inv[cbl[i]] = i;   // perm is a permutation: direct store == scatter-add on zeros
}

__global__ void k_comm(const int* __restrict__ cbl, const int* __restrict__ inv,
                       int* __restrict__ comm, int* __restrict__ idx0,
                       int* __restrict__ counts, int N) {
    __shared__ int h[NCOMM];
    int t = threadIdx.x;
    h[t] = 0; h[t + 256] = 0;
    __syncthreads();
    int j = blockIdx.x * 256 + t;
    if (j < N) {
        int ij = inv[j];
        int c  = cbl[N + ij];
        comm[j] = c;
        idx0[j] = cbl[ij];
        atomicAdd(&h[c], 1);
    }
    __syncthreads();
    int v = h[t];        if (v) atomicAdd(&counts[t], v);
    v = h[t + 256];      if (v) atomicAdd(&counts[t + 256], v);
}

__global__ void k_scan(const int* __restrict__ counts, int* __restrict__ offsets,
                       int* __restrict__ cursor, float* __restrict__ countf) {
    __shared__ int sc[NCOMM];
    int t = threadIdx.x;
    int v0 = counts[t];
    sc[t] = v0;
    __syncthreads();
    for (int off = 1; off < NCOMM; off <<= 1) {
        int v = (t >= off) ? sc[t - off] : 0;
        __syncthreads();
        sc[t] += v;
        __syncthreads();
    }
    int excl = sc[t] - v0;
    offsets[t] = excl;
    cursor[t]  = excl;
    countf[t]  = (float)v0;
}

// 1024 elements per block: LDS histogram + one range-reservation atomic per present comm
__global__ void k_sort(const int* __restrict__ comm, int* __restrict__ cursor,
                       int* __restrict__ sorted, int N) {
    __shared__ int h[NCOMM], hb[NCOMM];
    int t = threadIdx.x;
    h[t] = 0; h[t + 256] = 0;
    __syncthreads();
    int j0 = blockIdx.x * 1024 + t;
    int cs[4];
    #pragma unroll
    for (int q = 0; q < 4; ++q) {
        int j = j0 + q * 256;
        cs[q] = (j < N) ? comm[j] : -1;
        if (cs[q] >= 0) atomicAdd(&h[cs[q]], 1);
    }
    __syncthreads();
    int v = h[t];        if (v) hb[t] = atomicAdd(&cursor[t], v);
    v = h[t + 256];      if (v) hb[t + 256] = atomicAdd(&cursor[t + 256], v);
    __syncthreads();
    #pragma unroll
    for (int q = 0; q < 4; ++q) {
        int j = j0 + q * 256;
        if (cs[q] >= 0) {
            int p = atomicAdd(&hb[cs[q]], 1);
            sorted[p] = j;
        }
    }
}

// ---------------- per-community stats: float4 gather, single pass ----------------
// var = (sumsq - cnt*m^2)/(cnt-1): benign cancellation (x~N(0,1), rel err ~1e-6)

__global__ void __launch_bounds__(256) k_stats(
        const float* __restrict__ NF, const int* __restrict__ idx0,
        const int* __restrict__ sorted, const int* __restrict__ offsets,
        const int* __restrict__ counts,
        float* __restrict__ comm_sum,
        unsigned short* __restrict__ CMh, unsigned short* __restrict__ CMl,
        float* __restrict__ c2, float* __restrict__ accum) {
    __shared__ int ridx[512];
    __shared__ float4 bufS[256], bufQ[256];
    int c = blockIdx.x, t = threadIdx.x;
    int d4 = t & 31, r = t >> 5;                 // 32 dim-quads x 8 row slots
    int cnt = counts[c], base = offsets[c];
    const float4* NF4 = (const float4*)NF;

    float4 s4 = make_float4(0.f, 0.f, 0.f, 0.f);
    float4 q4 = make_float4(0.f, 0.f, 0.f, 0.f);
    for (int chunk = 0; chunk < cnt; chunk += 512) {
        int m = min(cnt - chunk, 512);
        for (int i = t; i < m; i += 256) ridx[i] = idx0[sorted[base + chunk + i]];
        __syncthreads();
        for (int i = r; i < m; i += 8) {
            float4 v = NF4[(size_t)ridx[i] * 32 + d4];
            s4.x += v.x; s4.y += v.y; s4.z += v.z; s4.w += v.w;
            q4.x = fmaf(v.x, v.x, q4.x); q4.y = fmaf(v.y, v.y, q4.y);
            q4.z = fmaf(v.z, v.z, q4.z); q4.w = fmaf(v.w, v.w, q4.w);
        }
        __syncthreads();
    }
    bufS[t] = s4; bufQ[t] = q4;
    __syncthreads();
    if (t < 128) {
        float4 a = bufS[t], b = bufS[t + 128];
        a.x += b.x; a.y += b.y; a.z += b.z; a.w += b.w; bufS[t] = a;
        float4 e = bufQ[t], f = bufQ[t + 128];
        e.x += f.x; e.y += f.y; e.z += f.z; e.w += f.w; bufQ[t] = e;
    }
    __syncthreads();
    if (t < 64) {
        float4 a = bufS[t], b = bufS[t + 64];
        a.x += b.x; a.y += b.y; a.z += b.z; a.w += b.w; bufS[t] = a;
        float4 e = bufQ[t], f = bufQ[t + 64];
        e.x += f.x; e.y += f.y; e.z += f.z; e.w += f.w; bufQ[t] = e;
    }
    __syncthreads();
    if (t < 32) {
        float4 a = bufS[t], b = bufS[t + 32];
        a.x += b.x; a.y += b.y; a.z += b.z; a.w += b.w;
        float4 e = bufQ[t], f = bufQ[t + 32];
        e.x += f.x; e.y += f.y; e.z += f.z; e.w += f.w;
        float sarr[4] = {a.x, a.y, a.z, a.w};
        float qarr[4] = {e.x, e.y, e.z, e.w};
        float cf = (float)cnt;
        float mm = 0.f, ee = 0.f;
        #pragma unroll
        for (int k = 0; k < 4; ++k) {
            int d = t * 4 + k;
            float s = sarr[k];
            comm_sum[c * DIM + d] = s;
            float m = (cnt > 0) ? s / cf : 0.f;
            unsigned short h = bf16_rn(m);
            CMh[c * DIM + d] = h;
            CMl[c * DIM + d] = bf16_rn(m - bf16_f(h));
            float varn = fmaxf(fmaf(-cf * m, m, qarr[k]), 0.f);
            float stdv = sqrtf(varn / fmaxf(cf - 1.f, 1.f));
            float er = stdv - 1.f;
            mm = fmaf(m, m, mm);
            ee = fmaf(er, er, ee);
        }
        #pragma unroll
        for (int msk = 1; msk < 32; msk <<= 1) {
            mm += __shfl_xor(mm, msk);
            ee += __shfl_xor(ee, msk);
        }
        if (t == 0) {
            c2[c] = mm;
            atomicAdd(&accum[2], ee);
        }
    }
}

// ---------------- heavy kernel: MFMA distances + triplet terms ----------------
// 512 threads (8 waves), 256 nodes/block, all 512 comms in 8 LDS-staged tiles of 64.
// bf16 hi/lo split (3 MFMAs) ~= fp32. A frags in registers for whole kernel.
// B staged global->LDS once per block via global_load_lds (pre-swizzled source
// addresses, linear LDS dest: rule #21), double-buffered; ds_read_b128 frags
// with chunk^row XOR -> <=2-way bank aliasing (free).

__global__ void __launch_bounds__(512, 2) k_main(
        const float* __restrict__ NF,
        const unsigned short* __restrict__ CMh,
        const unsigned short* __restrict__ CMl,
        const float* __restrict__ comm_sum,
        const float* __restrict__ c2g,
        const float* __restrict__ countf,
        const int* __restrict__ comm,
        const int* __restrict__ idx0,
        float* __restrict__ accum, int N) {
    __shared__ unsigned short BhL[2][64 * DIM];   // 16 KB per buffer
    __shared__ unsigned short BlL[2][64 * DIM];
    __shared__ float c2s[NCOMM];
    __shared__ int   comms[256];
    __shared__ float x2s[256];
    __shared__ float sums[256], mins[256], owns[256];
    __shared__ float red[16];

    int tid = threadIdx.x;
    int w  = tid >> 6;    // wave 0..7
    int l  = tid & 63;
    int lr = l & 15;      // A row within 16-frag / B (comm) col
    int lk = l >> 4;      // k-group
    int n0 = blockIdx.x * 256;

    c2s[tid] = c2g[tid];
    if (tid < 256) {
        int gn = n0 + tid;
        comms[tid] = (gn < N) ? comm[gn] : -1;
    }

    // stage B tile 0 (issue async; pre-swizzled global source, linear LDS dest)
    auto stage = [&](int tt, int b) {
        int c0 = tt * 64;
        #pragma unroll
        for (int q = 0; q < 2; ++q) {
            int p = q * 512 + w * 64 + l;          // linear 16B-chunk id 0..1023
            int row = p >> 4, cp = p & 15;
            size_t gch = ((size_t)(c0 + row) * 16 + (cp ^ (row & 15))) * 8;
            unsigned short* lh = &BhL[b][(size_t)(q * 512 + w * 64) * 8]; // wave-uniform
            unsigned short* ll = &BlL[b][(size_t)(q * 512 + w * 64) * 8];
            GLOAD_LDS16(CMh + gch, lh);
            GLOAD_LDS16(CMl + gch, ll);
        }
    };
    stage(0, 0);

    // ---- A fragments (rows w*32 + mf*16 + lr) + exact fp32 x2
    bf16x8 ah[2][4], al[2][4];
    #pragma unroll
    for (int mf = 0; mf < 2; ++mf) {
        int n = n0 + w * 32 + mf * 16 + lr;
        const float4* src = (const float4*)NF + (size_t)n * 32 + lk * 2;
        float p2 = 0.f;
        #pragma unroll
        for (int ks = 0; ks < 4; ++ks) {
            float4 v0 = make_float4(0.f, 0.f, 0.f, 0.f), v1 = v0;
            if (n < N) { v0 = src[ks * 8]; v1 = src[ks * 8 + 1]; }
            float fr[8] = {v0.x, v0.y, v0.z, v0.w, v1.x, v1.y, v1.z, v1.w};
            bf16x8 hh, ll;
            #pragma unroll
            for (int t = 0; t < 8; ++t) {
                unsigned short h = bf16_rn(fr[t]);
                hh[t] = (short)h;
                ll[t] = (short)bf16_rn(fr[t] - bf16_f(h));
                p2 = fmaf(fr[t], fr[t], p2);
            }
            ah[mf][ks] = hh; al[mf][ks] = ll;
        }
        p2 += __shfl_xor(p2, 16);
        p2 += __shfl_xor(p2, 32);
        if (lk == 0) x2s[w * 32 + mf * 16 + lr] = p2;
    }
    __syncthreads();   // tile0 staged + x2s/comms ready

    // per-lane per-row state (C layout: row = lk*4 + j, col = lr)
    float x2v[2][4], sumv[2][4], minv[2][4];
    int cnv[2][4];
    #pragma unroll
    for (int mf = 0; mf < 2; ++mf)
        #pragma unroll
        for (int j = 0; j < 4; ++j) {
            int idx = w * 32 + mf * 16 + lk * 4 + j;
            x2v[mf][j] = x2s[idx];
            cnv[mf][j] = comms[idx];
            sumv[mf][j] = 0.f; minv[mf][j] = BIGF;
        }

    int buf = 0;
    for (int tt = 0; tt < 8; ++tt) {
        if (tt + 1 < 8) stage(tt + 1, buf ^ 1);

        for (int s = 0; s < 4; ++s) {
            int rbase = s * 16 + lr;
            bf16x8 bh[4], bl[4];
            #pragma unroll
            for (int ks = 0; ks < 4; ++ks) {
                int ch = (ks * 4 + lk) ^ lr;      // matches staging swizzle (row&15 == lr)
                bh[ks] = *(const bf16x8*)&BhL[buf][(size_t)(rbase * 16 + ch) * 8];
                bl[ks] = *(const bf16x8*)&BlL[buf][(size_t)(rbase * 16 + ch) * 8];
            }
            f32x4 acc0 = {0.f, 0.f, 0.f, 0.f}, acc1 = acc0;
            #pragma unroll
            for (int ks = 0; ks < 4; ++ks) {
                acc0 = __builtin_amdgcn_mfma_f32_16x16x32_bf16(ah[0][ks], bh[ks], acc0, 0, 0, 0);
                acc1 = __builtin_amdgcn_mfma_f32_16x16x32_bf16(ah[1][ks], bh[ks], acc1, 0, 0, 0);
                acc0 = __builtin_amdgcn_mfma_f32_16x16x32_bf16(al[0][ks], bh[ks], acc0, 0, 0, 0);
                acc1 = __builtin_amdgcn_mfma_f32_16x16x32_bf16(al[1][ks], bh[ks], acc1, 0, 0, 0);
                acc0 = __builtin_amdgcn_mfma_f32_16x16x32_bf16(ah[0][ks], bl[ks], acc0, 0, 0, 0);
                acc1 = __builtin_amdgcn_mfma_f32_16x16x32_bf16(ah[1][ks], bl[ks], acc1, 0, 0, 0);
            }
            int ccol = tt * 64 + s * 16 + lr;
            float c2v = c2s[ccol];
            #pragma unroll
            for (int j = 0; j < 4; ++j) {
                float d2a = fmaf(-2.f, acc0[j], x2v[0][j] + c2v);
                float da  = sqrtf(fmaxf(d2a, 0.f));
                sumv[0][j] += da;
                bool oa = (cnv[0][j] == ccol);
                if (oa) owns[w * 32 + lk * 4 + j] = da;
                minv[0][j] = oa ? minv[0][j] : fminf(minv[0][j], da);
                float d2b = fmaf(-2.f, acc1[j], x2v[1][j] + c2v);
                float db  = sqrtf(fmaxf(d2b, 0.f));
                sumv[1][j] += db;
                bool ob = (cnv[1][j] == ccol);
                if (ob) owns[w * 32 + 16 + lk * 4 + j] = db;
                minv[1][j] = ob ? minv[1][j] : fminf(minv[1][j], db);
            }
        }
        __syncthreads();   // staging for tt+1 landed; all waves done reading buf
        buf ^= 1;
    }

    // reduce sum/min across the 16 lr lanes sharing each node row
    #pragma unroll
    for (int mf = 0; mf < 2; ++mf)
        #pragma unroll
        for (int j = 0; j < 4; ++j) {
            float sv = sumv[mf][j], mv = minv[mf][j];
            #pragma unroll
            for (int msk = 1; msk < 16; msk <<= 1) {
                sv += __shfl_xor(sv, msk);
                mv = fminf(mv, __shfl_xor(mv, msk));
            }
            if (lr == 0) {
                int idx = w * 32 + mf * 16 + lk * 4 + j;
                sums[idx] = sv; mins[idx] = mv;
            }
        }
    __syncthreads();

    // LOO positive distance + triplet terms (2 threads per node)
    float tmean = 0.f, tminv = 0.f;
    {
        int ln = tid >> 1, half = tid & 1;
        int n = n0 + ln;
        if (n < N) {
            int cnode = comms[ln];
            float cf  = countf[cnode];
            float cm1 = fmaxf(cf - 1.f, 1.f);
            float rs  = 1.f / cm1;
            bool single = (cf == 1.f);
            const float4* srow = (const float4*)(NF + (size_t)idx0[n] * DIM) + half * 16;
            const float4* csum = (const float4*)(comm_sum + (size_t)cnode * DIM) + half * 16;
            float q = 0.f;
            #pragma unroll
            for (int m = 0; m < 16; ++m) {
                float4 sv = srow[m];
                float4 cs = csum[m];
                float4 xm = single ? make_float4(0.f, 0.f, 0.f, 0.f) : sv;
                float lx = (cs.x - xm.x) * rs - sv.x + PEPS;
                float ly = (cs.y - xm.y) * rs - sv.y + PEPS;
                float lz = (cs.z - xm.z) * rs - sv.z + PEPS;
                float lw = (cs.w - xm.w) * rs - sv.w + PEPS;
                q = fmaf(lx, lx, fmaf(ly, ly, fmaf(lz, lz, fmaf(lw, lw, q))));
            }
            q += __shfl_xor(q, 1);
            if (half == 0) {
                float pos = sqrtf(q);
                float own = owns[ln];
                float mean_neg = (sums[ln] - own) * (1.f / (float)(NCOMM - 1));
                tmean = fmaxf(pos - mean_neg + ALPHA, 0.f);
                tminv = fmaxf(pos - mins[ln] + ALPHA, 0.f);
            }
        }
    }
    // block reduction of triplet sums
    #pragma unroll
    for (int msk = 1; msk < 64; msk <<= 1) {
        tmean += __shfl_xor(tmean, msk);
        tminv += __shfl_xor(tminv, msk);
    }
    if ((tid & 63) == 0) { red[w * 2] = tmean; red[w * 2 + 1] = tminv; }
    __syncthreads();
    if (tid == 0) {
        float a0 = 0.f, a1 = 0.f;
        #pragma unroll
        for (int i = 0; i < 8; ++i) { a0 += red[i * 2]; a1 += red[i * 2 + 1]; }
        atomicAdd(&accum[0], a0);
        atomicAdd(&accum[1], a1);
    }
}

__global__ void k_final(const float* __restrict__ accum, float* __restrict__ out, int N) {
    if (threadIdx.x == 0) {
        out[0] = accum[0] / (float)N;
        out[1] = accum[1] / (float)N;
        out[2] = accum[2] / (float)(NCOMM * DIM);
    }
}

// ---------------- launch ----------------

extern "C" void kernel_launch(void* const* d_in, const int* in_sizes, int n_in,
                              void* d_out, int out_size, void* d_ws, size_t ws_size,
                              hipStream_t stream) {
    const float* NF  = (const float*)d_in[0];
    const int*   CBL = (const int*)d_in[1];
    int N = in_sizes[1] / 2;
    if (N <= 0) return;

    char* ws = (char*)d_ws;
    float* accum   = (float*)ws;                    // 16 B
    int*   counts  = (int*)(ws + 16);               // 2048
    int*   cursor  = (int*)(ws + 16 + 2048);
    int*   offsets = (int*)(ws + 16 + 2 * 2048);
    float* countf  = (float*)(ws + 16 + 3 * 2048);
    float* c2      = (float*)(ws + 16 + 4 * 2048);
    char* p = ws + 16 + 5 * 2048;
    int* inv    = (int*)p; p += (size_t)N * 4;
    int* comm   = (int*)p; p += (size_t)N * 4;
    int* idx0   = (int*)p; p += (size_t)N * 4;
    int* sorted = (int*)p; p += (size_t)N * 4;
    float* comm_sum = (float*)p; p += (size_t)NCOMM * DIM * 4;
    unsigned short* CMh = (unsigned short*)p; p += (size_t)NCOMM * DIM * 2;
    unsigned short* CMl = (unsigned short*)p;

    hipMemsetAsync(d_ws, 0, 16 + 2048, stream);     // accum + counts

    int nb = (N + 255) / 256;
    k_inv <<<nb, 256, 0, stream>>>(CBL, inv, N);
    k_comm<<<nb, 256, 0, stream>>>(CBL, inv, comm, idx0, counts, N);
    k_scan<<<1, NCOMM, 0, stream>>>(counts, offsets, cursor, countf);
    int nb4 = (N + 1023) / 1024;
    k_sort<<<nb4, 256, 0, stream>>>(comm, cursor, sorted, N);
    k_stats<<<NCOMM, 256, 0, stream>>>(NF, idx0, sorted, offsets, counts,
                                       comm_sum, CMh, CMl, c2, accum);
    int mb = (N + 255) / 256;
    k_main<<<mb, 512, 0, stream>>>(NF, CMh, CMl, comm_sum, c2, countf,
                                   comm, idx0, accum, N);
    k_final<<<1, 64, 0, stream>>>(accum, (float*)d_out, N);
}

// Round 3
// 151.669 us; speedup vs baseline: 4.0284x; 1.1049x over previous
//
#include <hip/hip_runtime.h>

#define NCOMM 512
#define DIM   128
#define ALPHA 0.25f
#define PEPS  1e-6f
#define BIGF  1e30f
#define TILE_C 32
#define NT    (NCOMM / TILE_C)

typedef __attribute__((ext_vector_type(8))) short bf16x8;
typedef __attribute__((ext_vector_type(4))) float f32x4;

__device__ __forceinline__ unsigned short bf16_rn(float v) {
    unsigned u = __float_as_uint(v);
    u += 0x7FFFu + ((u >> 16) & 1u);
    return (unsigned short)(u >> 16);
}
__device__ __forceinline__ float bf16_f(unsigned short h) {
    return __uint_as_float((unsigned)h << 16);
}

#define GLOAD_LDS16(g, l) __builtin_amdgcn_global_load_lds( \
    (const __attribute__((address_space(1))) void*)(g), \
    (__attribute__((address_space(3))) void*)(l), 16, 0, 0)

// ---------------- small prep kernels ----------------

__global__ void k_inv(const int* __restrict__ cbl, int* __restrict__ inv, int N) {
    int i = blockIdx.x * 256 + threadIdx.x;
    if (i < N) inv[cbl[i]] = i;   // perm is a permutation: direct store == scatter-add on zeros
}

__global__ void k_comm(const int* __restrict__ cbl, const int* __restrict__ inv,
                       int* __restrict__ comm, int* __restrict__ idx0,
                       int* __restrict__ counts, int N) {
    __shared__ int h[NCOMM];
    int t = threadIdx.x;
    h[t] = 0; h[t + 256] = 0;
    __syncthreads();
    int j = blockIdx.x * 256 + t;
    if (j < N) {
        int ij = inv[j];
        int c  = cbl[N + ij];
        comm[j] = c;
        idx0[j] = cbl[ij];
        atomicAdd(&h[c], 1);
    }
    __syncthreads();
    int v = h[t];        if (v) atomicAdd(&counts[t], v);
    v = h[t + 256];      if (v) atomicAdd(&counts[t + 256], v);
}

__global__ void k_scan(const int* __restrict__ counts, int* __restrict__ offsets,
                       int* __restrict__ cursor, float* __restrict__ countf) {
    __shared__ int sc[NCOMM];
    int t = threadIdx.x;
    int v0 = counts[t];
    sc[t] = v0;
    __syncthreads();
    for (int off = 1; off < NCOMM; off <<= 1) {
        int v = (t >= off) ? sc[t - off] : 0;
        __syncthreads();
        sc[t] += v;
        __syncthreads();
    }
    int excl = sc[t] - v0;
    offsets[t] = excl;
    cursor[t]  = excl;
    countf[t]  = (float)v0;
}

// 1024 elements per block: LDS histogram + one range-reservation atomic per present comm
__global__ void k_sort(const int* __restrict__ comm, int* __restrict__ cursor,
                       int* __restrict__ sorted, int N) {
    __shared__ int h[NCOMM], hb[NCOMM];
    int t = threadIdx.x;
    h[t] = 0; h[t + 256] = 0;
    __syncthreads();
    int j0 = blockIdx.x * 1024 + t;
    int cs[4];
    #pragma unroll
    for (int q = 0; q < 4; ++q) {
        int j = j0 + q * 256;
        cs[q] = (j < N) ? comm[j] : -1;
        if (cs[q] >= 0) atomicAdd(&h[cs[q]], 1);
    }
    __syncthreads();
    int v = h[t];        if (v) hb[t] = atomicAdd(&cursor[t], v);
    v = h[t + 256];      if (v) hb[t + 256] = atomicAdd(&cursor[t + 256], v);
    __syncthreads();
    #pragma unroll
    for (int q = 0; q < 4; ++q) {
        int j = j0 + q * 256;
        if (cs[q] >= 0) {
            int p = atomicAdd(&hb[cs[q]], 1);
            sorted[p] = j;
        }
    }
}

// ---------------- per-community stats: float4 gather, single pass ----------------
// var = (sumsq - cnt*m^2)/(cnt-1): benign cancellation (x~N(0,1), rel err ~1e-6)

__global__ void __launch_bounds__(256) k_stats(
        const float* __restrict__ NF, const int* __restrict__ idx0,
        const int* __restrict__ sorted, const int* __restrict__ offsets,
        const int* __restrict__ counts,
        float* __restrict__ comm_sum,
        unsigned short* __restrict__ CMh, unsigned short* __restrict__ CMl,
        float* __restrict__ c2, float* __restrict__ accum) {
    __shared__ int ridx[512];
    __shared__ float4 bufS[256], bufQ[256];
    int c = blockIdx.x, t = threadIdx.x;
    int d4 = t & 31, r = t >> 5;                 // 32 dim-quads x 8 row slots
    int cnt = counts[c], base = offsets[c];
    const float4* NF4 = (const float4*)NF;

    float4 s4 = make_float4(0.f, 0.f, 0.f, 0.f);
    float4 q4 = make_float4(0.f, 0.f, 0.f, 0.f);
    for (int chunk = 0; chunk < cnt; chunk += 512) {
        int m = min(cnt - chunk, 512);
        for (int i = t; i < m; i += 256) ridx[i] = idx0[sorted[base + chunk + i]];
        __syncthreads();
        for (int i = r; i < m; i += 8) {
            float4 v = NF4[(size_t)ridx[i] * 32 + d4];
            s4.x += v.x; s4.y += v.y; s4.z += v.z; s4.w += v.w;
            q4.x = fmaf(v.x, v.x, q4.x); q4.y = fmaf(v.y, v.y, q4.y);
            q4.z = fmaf(v.z, v.z, q4.z); q4.w = fmaf(v.w, v.w, q4.w);
        }
        __syncthreads();
    }
    bufS[t] = s4; bufQ[t] = q4;
    __syncthreads();
    if (t < 128) {
        float4 a = bufS[t], b = bufS[t + 128];
        a.x += b.x; a.y += b.y; a.z += b.z; a.w += b.w; bufS[t] = a;
        float4 e = bufQ[t], f = bufQ[t + 128];
        e.x += f.x; e.y += f.y; e.z += f.z; e.w += f.w; bufQ[t] = e;
    }
    __syncthreads();
    if (t < 64) {
        float4 a = bufS[t], b = bufS[t + 64];
        a.x += b.x; a.y += b.y; a.z += b.z; a.w += b.w; bufS[t] = a;
        float4 e = bufQ[t], f = bufQ[t + 64];
        e.x += f.x; e.y += f.y; e.z += f.z; e.w += f.w; bufQ[t] = e;
    }
    __syncthreads();
    if (t < 32) {
        float4 a = bufS[t], b = bufS[t + 32];
        a.x += b.x; a.y += b.y; a.z += b.z; a.w += b.w;
        float4 e = bufQ[t], f = bufQ[t + 32];
        e.x += f.x; e.y += f.y; e.z += f.z; e.w += f.w;
        float sarr[4] = {a.x, a.y, a.z, a.w};
        float qarr[4] = {e.x, e.y, e.z, e.w};
        float cf = (float)cnt;
        float mm = 0.f, ee = 0.f;
        #pragma unroll
        for (int k = 0; k < 4; ++k) {
            int d = t * 4 + k;
            float s = sarr[k];
            comm_sum[c * DIM + d] = s;
            float m = (cnt > 0) ? s / cf : 0.f;
            unsigned short h = bf16_rn(m);
            CMh[c * DIM + d] = h;
            CMl[c * DIM + d] = bf16_rn(m - bf16_f(h));
            float varn = fmaxf(fmaf(-cf * m, m, qarr[k]), 0.f);
            float stdv = sqrtf(varn / fmaxf(cf - 1.f, 1.f));
            float er = stdv - 1.f;
            mm = fmaf(m, m, mm);
            ee = fmaf(er, er, ee);
        }
        #pragma unroll
        for (int msk = 1; msk < 32; msk <<= 1) {
            mm += __shfl_xor(mm, msk);
            ee += __shfl_xor(ee, msk);
        }
        if (t == 0) {
            c2[c] = mm;
            atomicAdd(&accum[2], ee);
        }
    }
}

// ---------------- heavy kernel: MFMA distances + triplet terms ----------------
// 256 threads (4 waves x 32 rows = 128 nodes/block), 16 comm-tiles of 32, LDS dbuf.
// __launch_bounds__(256,3): 3 waves/SIMD -> 3 blocks/CU = 12 waves/CU.
// 4 independent MFMA chains (2 mf x ks-parity, depth 6) merged with 2 vector adds.
// Epilogue: raw v_sqrt, register own via cndmask, min-exclude via cndmask+fmin.

__global__ void __launch_bounds__(256, 3) k_main(
        const float* __restrict__ NF,
        const unsigned short* __restrict__ CMh,
        const unsigned short* __restrict__ CMl,
        const float* __restrict__ comm_sum,
        const float* __restrict__ c2g,
        const float* __restrict__ countf,
        const int* __restrict__ comm,
        const int* __restrict__ idx0,
        float* __restrict__ accum, int N) {
    __shared__ unsigned short BhL[2][TILE_C * DIM];   // 8 KB each buf
    __shared__ unsigned short BlL[2][TILE_C * DIM];
    __shared__ float c2s[NCOMM];
    __shared__ int   comms[128];
    __shared__ float x2s[128];
    __shared__ float sums[128], mins[128], owns[128];
    __shared__ float red[8];

    int tid = threadIdx.x;
    int w  = tid >> 6;    // wave 0..3
    int l  = tid & 63;
    int lr = l & 15;      // A row within 16-frag / B (comm) col
    int lk = l >> 4;      // k-group
    int n0 = blockIdx.x * 128;

    // stage B tile 0 first (oldest in vmem queue; hides under A conversion)
    auto stage = [&](int tt, int b) {
        int c0 = tt * TILE_C;
        #pragma unroll
        for (int q = 0; q < 2; ++q) {
            int p = q * 256 + tid;                 // linear 16B-chunk id 0..511
            int row = p >> 4, cp = p & 15;
            size_t gch = ((size_t)(c0 + row) * 16 + (cp ^ (row & 15))) * 8;
            unsigned short* lh = &BhL[b][(size_t)(q * 256 + w * 64) * 8]; // wave-uniform
            unsigned short* ll = &BlL[b][(size_t)(q * 256 + w * 64) * 8];
            GLOAD_LDS16(CMh + gch, lh);
            GLOAD_LDS16(CMl + gch, ll);
        }
    };
    stage(0, 0);

    c2s[tid]       = c2g[tid];
    c2s[tid + 256] = c2g[tid + 256];
    if (tid < 128) {
        int gn = n0 + tid;
        comms[tid] = (gn < N) ? comm[gn] : -1;
    }

    // ---- A fragments (rows w*32 + mf*16 + lr) + exact fp32 x2
    bf16x8 ah[2][4], al[2][4];
    #pragma unroll
    for (int mf = 0; mf < 2; ++mf) {
        int n = n0 + w * 32 + mf * 16 + lr;
        const float4* src = (const float4*)NF + (size_t)n * 32 + lk * 2;
        float p2 = 0.f;
        #pragma unroll
        for (int ks = 0; ks < 4; ++ks) {
            float4 v0 = make_float4(0.f, 0.f, 0.f, 0.f), v1 = v0;
            if (n < N) { v0 = src[ks * 8]; v1 = src[ks * 8 + 1]; }
            float fr[8] = {v0.x, v0.y, v0.z, v0.w, v1.x, v1.y, v1.z, v1.w};
            bf16x8 hh, ll;
            #pragma unroll
            for (int t = 0; t < 8; ++t) {
                unsigned short h = bf16_rn(fr[t]);
                hh[t] = (short)h;
                ll[t] = (short)bf16_rn(fr[t] - bf16_f(h));
                p2 = fmaf(fr[t], fr[t], p2);
            }
            ah[mf][ks] = hh; al[mf][ks] = ll;
        }
        p2 += __shfl_xor(p2, 16);
        p2 += __shfl_xor(p2, 32);
        if (lk == 0) x2s[w * 32 + mf * 16 + lr] = p2;
    }
    __syncthreads();   // tile0 staged + x2s/comms/c2s ready

    // per-lane per-row state (C layout: row = lk*4 + j, col = lr)
    float x2v[2][4], sumv[2][4], minv[2][4], ownv[2][4];
    int cnv[2][4];
    #pragma unroll
    for (int mf = 0; mf < 2; ++mf)
        #pragma unroll
        for (int j = 0; j < 4; ++j) {
            int idx = w * 32 + mf * 16 + lk * 4 + j;
            x2v[mf][j] = x2s[idx];
            cnv[mf][j] = comms[idx];
            sumv[mf][j] = 0.f; minv[mf][j] = BIGF; ownv[mf][j] = 0.f;
        }

    int buf = 0;
    for (int tt = 0; tt < NT; ++tt) {
        if (tt + 1 < NT) stage(tt + 1, buf ^ 1);

        #pragma unroll
        for (int s = 0; s < 2; ++s) {
            int rbase = s * 16 + lr;
            f32x4 ae0 = {0.f, 0.f, 0.f, 0.f}, ao0 = ae0, ae1 = ae0, ao1 = ae0;
            #pragma unroll
            for (int hf = 0; hf < 2; ++hf) {           // ks pair {2hf, 2hf+1}
                int ke = hf * 2, ko = hf * 2 + 1;
                int che = (ke * 4 + lk) ^ lr;
                int cho = (ko * 4 + lk) ^ lr;
                bf16x8 bhe = *(const bf16x8*)&BhL[buf][(size_t)(rbase * 16 + che) * 8];
                bf16x8 bho = *(const bf16x8*)&BhL[buf][(size_t)(rbase * 16 + cho) * 8];
                bf16x8 ble = *(const bf16x8*)&BlL[buf][(size_t)(rbase * 16 + che) * 8];
                bf16x8 blo = *(const bf16x8*)&BlL[buf][(size_t)(rbase * 16 + cho) * 8];
                ae0 = __builtin_amdgcn_mfma_f32_16x16x32_bf16(ah[0][ke], bhe, ae0, 0, 0, 0);
                ae1 = __builtin_amdgcn_mfma_f32_16x16x32_bf16(ah[1][ke], bhe, ae1, 0, 0, 0);
                ao0 = __builtin_amdgcn_mfma_f32_16x16x32_bf16(ah[0][ko], bho, ao0, 0, 0, 0);
                ao1 = __builtin_amdgcn_mfma_f32_16x16x32_bf16(ah[1][ko], bho, ao1, 0, 0, 0);
                ae0 = __builtin_amdgcn_mfma_f32_16x16x32_bf16(al[0][ke], bhe, ae0, 0, 0, 0);
                ae1 = __builtin_amdgcn_mfma_f32_16x16x32_bf16(al[1][ke], bhe, ae1, 0, 0, 0);
                ao0 = __builtin_amdgcn_mfma_f32_16x16x32_bf16(al[0][ko], bho, ao0, 0, 0, 0);
                ao1 = __builtin_amdgcn_mfma_f32_16x16x32_bf16(al[1][ko], bho, ao1, 0, 0, 0);
                ae0 = __builtin_amdgcn_mfma_f32_16x16x32_bf16(ah[0][ke], ble, ae0, 0, 0, 0);
                ae1 = __builtin_amdgcn_mfma_f32_16x16x32_bf16(ah[1][ke], ble, ae1, 0, 0, 0);
                ao0 = __builtin_amdgcn_mfma_f32_16x16x32_bf16(ah[0][ko], blo, ao0, 0, 0, 0);
                ao1 = __builtin_amdgcn_mfma_f32_16x16x32_bf16(ah[1][ko], blo, ao1, 0, 0, 0);
            }
            f32x4 acc0 = ae0 + ao0;
            f32x4 acc1 = ae1 + ao1;
            int ccol = tt * TILE_C + s * 16 + lr;
            float c2v = c2s[ccol];
            #pragma unroll
            for (int j = 0; j < 4; ++j) {
                float d2a = fmaf(-2.f, acc0[j], x2v[0][j] + c2v);
                float da  = __builtin_amdgcn_sqrtf(fmaxf(d2a, 0.f));
                sumv[0][j] += da;
                bool oa = (cnv[0][j] == ccol);
                ownv[0][j] = oa ? da : ownv[0][j];
                minv[0][j] = fminf(minv[0][j], oa ? BIGF : da);
                float d2b = fmaf(-2.f, acc1[j], x2v[1][j] + c2v);
                float db  = __builtin_amdgcn_sqrtf(fmaxf(d2b, 0.f));
                sumv[1][j] += db;
                bool ob = (cnv[1][j] == ccol);
                ownv[1][j] = ob ? db : ownv[1][j];
                minv[1][j] = fminf(minv[1][j], ob ? BIGF : db);
            }
        }
        __syncthreads();   // staging for tt+1 landed; all waves done reading buf
        buf ^= 1;
    }

    // reduce sum/min/own across the 16 lr lanes sharing each node row
    #pragma unroll
    for (int mf = 0; mf < 2; ++mf)
        #pragma unroll
        for (int j = 0; j < 4; ++j) {
            float sv = sumv[mf][j], mv = minv[mf][j], ov = ownv[mf][j];
            #pragma unroll
            for (int msk = 1; msk < 16; msk <<= 1) {
                sv += __shfl_xor(sv, msk);
                mv = fminf(mv, __shfl_xor(mv, msk));
                ov += __shfl_xor(ov, msk);
            }
            if (lr == 0) {
                int idx = w * 32 + mf * 16 + lk * 4 + j;
                sums[idx] = sv; mins[idx] = mv; owns[idx] = ov;
            }
        }
    __syncthreads();

    // LOO positive distance + triplet terms (2 threads per node)
    float tmean = 0.f, tminv = 0.f;
    {
        int ln = tid >> 1, half = tid & 1;
        int n = n0 + ln;
        if (n < N) {
            int cnode = comms[ln];
            float cf  = countf[cnode];
            float cm1 = fmaxf(cf - 1.f, 1.f);
            float rs  = 1.f / cm1;
            bool single = (cf == 1.f);
            const float4* srow = (const float4*)(NF + (size_t)idx0[n] * DIM) + half * 16;
            const float4* csum = (const float4*)(comm_sum + (size_t)cnode * DIM) + half * 16;
            float q = 0.f;
            #pragma unroll
            for (int m = 0; m < 16; ++m) {
                float4 sv = srow[m];
                float4 cs = csum[m];
                float4 xm = single ? make_float4(0.f, 0.f, 0.f, 0.f) : sv;
                float lx = (cs.x - xm.x) * rs - sv.x + PEPS;
                float ly = (cs.y - xm.y) * rs - sv.y + PEPS;
                float lz = (cs.z - xm.z) * rs - sv.z + PEPS;
                float lw = (cs.w - xm.w) * rs - sv.w + PEPS;
                q = fmaf(lx, lx, fmaf(ly, ly, fmaf(lz, lz, fmaf(lw, lw, q))));
            }
            q += __shfl_xor(q, 1);
            if (half == 0) {
                float pos = sqrtf(q);
                float own = owns[ln];
                float mean_neg = (sums[ln] - own) * (1.f / (float)(NCOMM - 1));
                tmean = fmaxf(pos - mean_neg + ALPHA, 0.f);
                tminv = fmaxf(pos - mins[ln] + ALPHA, 0.f);
            }
        }
    }
    // block reduction of triplet sums
    #pragma unroll
    for (int msk = 1; msk < 64; msk <<= 1) {
        tmean += __shfl_xor(tmean, msk);
        tminv += __shfl_xor(tminv, msk);
    }
    if ((tid & 63) == 0) { red[w * 2] = tmean; red[w * 2 + 1] = tminv; }
    __syncthreads();
    if (tid == 0) {
        atomicAdd(&accum[0], red[0] + red[2] + red[4] + red[6]);
        atomicAdd(&accum[1], red[1] + red[3] + red[5] + red[7]);
    }
}

__global__ void k_final(const float* __restrict__ accum, float* __restrict__ out, int N) {
    if (threadIdx.x == 0) {
        out[0] = accum[0] / (float)N;
        out[1] = accum[1] / (float)N;
        out[2] = accum[2] / (float)(NCOMM * DIM);
    }
}

// ---------------- launch ----------------

extern "C" void kernel_launch(void* const* d_in, const int* in_sizes, int n_in,
                              void* d_out, int out_size, void* d_ws, size_t ws_size,
                              hipStream_t stream) {
    const float* NF  = (const float*)d_in[0];
    const int*   CBL = (const int*)d_in[1];
    int N = in_sizes[1] / 2;
    if (N <= 0) return;

    char* ws = (char*)d_ws;
    float* accum   = (float*)ws;                    // 16 B
    int*   counts  = (int*)(ws + 16);               // 2048
    int*   cursor  = (int*)(ws + 16 + 2048);
    int*   offsets = (int*)(ws + 16 + 2 * 2048);
    float* countf  = (float*)(ws + 16 + 3 * 2048);
    float* c2      = (float*)(ws + 16 + 4 * 2048);
    char* p = ws + 16 + 5 * 2048;
    int* inv    = (int*)p; p += (size_t)N * 4;
    int* comm   = (int*)p; p += (size_t)N * 4;
    int* idx0   = (int*)p; p += (size_t)N * 4;
    int* sorted = (int*)p; p += (size_t)N * 4;
    float* comm_sum = (float*)p; p += (size_t)NCOMM * DIM * 4;
    unsigned short* CMh = (unsigned short*)p; p += (size_t)NCOMM * DIM * 2;
    unsigned short* CMl = (unsigned short*)p;

    hipMemsetAsync(d_ws, 0, 16 + 2048, stream);     // accum + counts

    int nb = (N + 255) / 256;
    k_inv <<<nb, 256, 0, stream>>>(CBL, inv, N);
    k_comm<<<nb, 256, 0, stream>>>(CBL, inv, comm, idx0, counts, N);
    k_scan<<<1, NCOMM, 0, stream>>>(counts, offsets, cursor, countf);
    int nb4 = (N + 1023) / 1024;
    k_sort<<<nb4, 256, 0, stream>>>(comm, cursor, sorted, N);
    k_stats<<<NCOMM, 256, 0, stream>>>(NF, idx0, sorted, offsets, counts,
                                       comm_sum, CMh, CMl, c2, accum);
    int mb = (N + 127) / 128;
    k_main<<<mb, 256, 0, stream>>>(NF, CMh, CMl, comm_sum, c2, countf,
                                   comm, idx0, accum, N);
    k_final<<<1, 64, 0, stream>>>(accum, (float*)d_out, N);
}

// Round 4
// 147.252 us; speedup vs baseline: 4.1492x; 1.0300x over previous
//
#include <hip/hip_runtime.h>

#define NCOMM 512
#define DIM   128
#define ALPHA 0.25f
#define PEPS  1e-6f
#define BIGF  1e30f
#define TILE_C 16
#define NT    (NCOMM / TILE_C)   // 32 tiles

typedef __attribute__((ext_vector_type(8))) short bf16x8;
typedef __attribute__((ext_vector_type(4))) float f32x4;

__device__ __forceinline__ unsigned short bf16_rn(float v) {
    unsigned u = __float_as_uint(v);
    u += 0x7FFFu + ((u >> 16) & 1u);
    return (unsigned short)(u >> 16);
}
__device__ __forceinline__ float bf16_f(unsigned short h) {
    return __uint_as_float((unsigned)h << 16);
}

#define GLOAD_LDS16(g, l) __builtin_amdgcn_global_load_lds( \
    (const __attribute__((address_space(1))) void*)(g), \
    (__attribute__((address_space(3))) void*)(l), 16, 0, 0)

// ---------------- small prep kernels ----------------

__global__ void k_inv(const int* __restrict__ cbl, int* __restrict__ inv, int N) {
    int i = blockIdx.x * 256 + threadIdx.x;
    if (i < N) inv[cbl[i]] = i;   // perm is a permutation: direct store == scatter-add on zeros
}

__global__ void k_comm(const int* __restrict__ cbl, const int* __restrict__ inv,
                       int* __restrict__ comm, int* __restrict__ idx0,
                       int* __restrict__ counts, int N) {
    __shared__ int h[NCOMM];
    int t = threadIdx.x;
    h[t] = 0; h[t + 256] = 0;
    __syncthreads();
    int j = blockIdx.x * 256 + t;
    if (j < N) {
        int ij = inv[j];
        int c  = cbl[N + ij];
        comm[j] = c;
        idx0[j] = cbl[ij];
        atomicAdd(&h[c], 1);
    }
    __syncthreads();
    int v = h[t];        if (v) atomicAdd(&counts[t], v);
    v = h[t + 256];      if (v) atomicAdd(&counts[t + 256], v);
}

__global__ void k_scan(const int* __restrict__ counts, int* __restrict__ offsets,
                       int* __restrict__ cursor, float* __restrict__ countf) {
    __shared__ int sc[NCOMM];
    int t = threadIdx.x;
    int v0 = counts[t];
    sc[t] = v0;
    __syncthreads();
    for (int off = 1; off < NCOMM; off <<= 1) {
        int v = (t >= off) ? sc[t - off] : 0;
        __syncthreads();
        sc[t] += v;
        __syncthreads();
    }
    int excl = sc[t] - v0;
    offsets[t] = excl;
    cursor[t]  = excl;
    countf[t]  = (float)v0;
}

// 1024 elements per block: LDS histogram + one range-reservation atomic per present comm
__global__ void k_sort(const int* __restrict__ comm, int* __restrict__ cursor,
                       int* __restrict__ sorted, int N) {
    __shared__ int h[NCOMM], hb[NCOMM];
    int t = threadIdx.x;
    h[t] = 0; h[t + 256] = 0;
    __syncthreads();
    int j0 = blockIdx.x * 1024 + t;
    int cs[4];
    #pragma unroll
    for (int q = 0; q < 4; ++q) {
        int j = j0 + q * 256;
        cs[q] = (j < N) ? comm[j] : -1;
        if (cs[q] >= 0) atomicAdd(&h[cs[q]], 1);
    }
    __syncthreads();
    int v = h[t];        if (v) hb[t] = atomicAdd(&cursor[t], v);
    v = h[t + 256];      if (v) hb[t + 256] = atomicAdd(&cursor[t + 256], v);
    __syncthreads();
    #pragma unroll
    for (int q = 0; q < 4; ++q) {
        int j = j0 + q * 256;
        if (cs[q] >= 0) {
            int p = atomicAdd(&hb[cs[q]], 1);
            sorted[p] = j;
        }
    }
}

// ---------------- per-community stats: float4 gather, single pass ----------------
// var = (sumsq - cnt*m^2)/(cnt-1): benign cancellation (x~N(0,1), rel err ~1e-6)

__global__ void __launch_bounds__(256) k_stats(
        const float* __restrict__ NF, const int* __restrict__ idx0,
        const int* __restrict__ sorted, const int* __restrict__ offsets,
        const int* __restrict__ counts,
        float* __restrict__ comm_sum,
        unsigned short* __restrict__ CMh, unsigned short* __restrict__ CMl,
        float* __restrict__ c2, float* __restrict__ accum) {
    __shared__ int ridx[512];
    __shared__ float4 bufS[256], bufQ[256];
    int c = blockIdx.x, t = threadIdx.x;
    int d4 = t & 31, r = t >> 5;                 // 32 dim-quads x 8 row slots
    int cnt = counts[c], base = offsets[c];
    const float4* NF4 = (const float4*)NF;

    float4 s4 = make_float4(0.f, 0.f, 0.f, 0.f);
    float4 q4 = make_float4(0.f, 0.f, 0.f, 0.f);
    for (int chunk = 0; chunk < cnt; chunk += 512) {
        int m = min(cnt - chunk, 512);
        for (int i = t; i < m; i += 256) ridx[i] = idx0[sorted[base + chunk + i]];
        __syncthreads();
        for (int i = r; i < m; i += 8) {
            float4 v = NF4[(size_t)ridx[i] * 32 + d4];
            s4.x += v.x; s4.y += v.y; s4.z += v.z; s4.w += v.w;
            q4.x = fmaf(v.x, v.x, q4.x); q4.y = fmaf(v.y, v.y, q4.y);
            q4.z = fmaf(v.z, v.z, q4.z); q4.w = fmaf(v.w, v.w, q4.w);
        }
        __syncthreads();
    }
    bufS[t] = s4; bufQ[t] = q4;
    __syncthreads();
    if (t < 128) {
        float4 a = bufS[t], b = bufS[t + 128];
        a.x += b.x; a.y += b.y; a.z += b.z; a.w += b.w; bufS[t] = a;
        float4 e = bufQ[t], f = bufQ[t + 128];
        e.x += f.x; e.y += f.y; e.z += f.z; e.w += f.w; bufQ[t] = e;
    }
    __syncthreads();
    if (t < 64) {
        float4 a = bufS[t], b = bufS[t + 64];
        a.x += b.x; a.y += b.y; a.z += b.z; a.w += b.w; bufS[t] = a;
        float4 e = bufQ[t], f = bufQ[t + 64];
        e.x += f.x; e.y += f.y; e.z += f.z; e.w += f.w; bufQ[t] = e;
    }
    __syncthreads();
    if (t < 32) {
        float4 a = bufS[t], b = bufS[t + 32];
        a.x += b.x; a.y += b.y; a.z += b.z; a.w += b.w;
        float4 e = bufQ[t], f = bufQ[t + 32];
        e.x += f.x; e.y += f.y; e.z += f.z; e.w += f.w;
        float sarr[4] = {a.x, a.y, a.z, a.w};
        float qarr[4] = {e.x, e.y, e.z, e.w};
        float cf = (float)cnt;
        float mm = 0.f, ee = 0.f;
        #pragma unroll
        for (int k = 0; k < 4; ++k) {
            int d = t * 4 + k;
            float s = sarr[k];
            comm_sum[c * DIM + d] = s;
            float m = (cnt > 0) ? s / cf : 0.f;
            unsigned short h = bf16_rn(m);
            CMh[c * DIM + d] = h;
            CMl[c * DIM + d] = bf16_rn(m - bf16_f(h));
            float varn = fmaxf(fmaf(-cf * m, m, qarr[k]), 0.f);
            float stdv = sqrtf(varn / fmaxf(cf - 1.f, 1.f));
            float er = stdv - 1.f;
            mm = fmaf(m, m, mm);
            ee = fmaf(er, er, ee);
        }
        #pragma unroll
        for (int msk = 1; msk < 32; msk <<= 1) {
            mm += __shfl_xor(mm, msk);
            ee += __shfl_xor(ee, msk);
        }
        if (t == 0) {
            c2[c] = mm;
            atomicAdd(&accum[2], ee);
        }
    }
}

// ---------------- heavy kernel: MFMA distances + triplet terms ----------------
// 256 threads (4 waves x 32 rows = 128 nodes/block). B tiles are WAVE-PRIVATE
// double-buffered LDS (TILE_C=16 comms): each wave stages its own tile with 8
// global_load_lds and syncs with counted s_waitcnt vmcnt(8) -- NO __syncthreads
// in the K-loop, loads for tile t+1 stay in flight across compute of tile t.
// XOR-swizzled (pre-swizzled global source, linear LDS dest, swizzled ds_read).
// own-distance recomputed exactly in the LOO phase (dot(srow,csum)) -> not
// tracked in the inner loop.

__global__ void __launch_bounds__(256, 2) k_main(
        const float* __restrict__ NF,
        const unsigned short* __restrict__ CMh,
        const unsigned short* __restrict__ CMl,
        const float* __restrict__ comm_sum,
        const float* __restrict__ c2g,
        const float* __restrict__ countf,
        const int* __restrict__ comm,
        const int* __restrict__ idx0,
        float* __restrict__ accum, int N) {
    __shared__ unsigned short Bst[4][2][2][TILE_C * DIM];  // [wave][buf][h/l] = 64 KB
    __shared__ float c2s[NCOMM];
    __shared__ int   comms[128];
    __shared__ float x2s[128];
    __shared__ float sums[128], mins[128];
    __shared__ float red[8];

    int tid = threadIdx.x;
    int w  = tid >> 6;    // wave 0..3
    int l  = tid & 63;
    int lr = l & 15;      // A row within 16-frag / B (comm) col
    int lk = l >> 4;      // k-group
    int n0 = blockIdx.x * 128;

    // per-wave stage of one 16-comm tile (8 x global_load_lds, 16B each lane)
    auto stage = [&](int tt, int b) {
        int c0 = tt * TILE_C;
        unsigned short* lh = &Bst[w][b][0][0];
        unsigned short* ll = &Bst[w][b][1][0];
        #pragma unroll
        for (int i = 0; i < 4; ++i) {
            int p = i * 64 + l;
            int row = p >> 4, cp = p & 15;
            size_t gch = ((size_t)(c0 + row) * 16 + (cp ^ row)) * 8;
            GLOAD_LDS16(CMh + gch, lh + i * 512);
            GLOAD_LDS16(CMl + gch, ll + i * 512);
        }
    };
    stage(0, 0);   // issued first; lands during A conversion

    c2s[tid]       = c2g[tid];
    c2s[tid + 256] = c2g[tid + 256];
    if (tid < 128) {
        int gn = n0 + tid;
        comms[tid] = (gn < N) ? comm[gn] : -1;
    }

    // ---- A fragments (rows w*32 + mf*16 + lr) + exact fp32 x2
    bf16x8 ah[2][4], al[2][4];
    #pragma unroll
    for (int mf = 0; mf < 2; ++mf) {
        int n = n0 + w * 32 + mf * 16 + lr;
        const float4* src = (const float4*)NF + (size_t)n * 32 + lk * 2;
        float p2 = 0.f;
        #pragma unroll
        for (int ks = 0; ks < 4; ++ks) {
            float4 v0 = make_float4(0.f, 0.f, 0.f, 0.f), v1 = v0;
            if (n < N) { v0 = src[ks * 8]; v1 = src[ks * 8 + 1]; }
            float fr[8] = {v0.x, v0.y, v0.z, v0.w, v1.x, v1.y, v1.z, v1.w};
            bf16x8 hh, ll;
            #pragma unroll
            for (int t = 0; t < 8; ++t) {
                unsigned short h = bf16_rn(fr[t]);
                hh[t] = (short)h;
                ll[t] = (short)bf16_rn(fr[t] - bf16_f(h));
                p2 = fmaf(fr[t], fr[t], p2);
            }
            ah[mf][ks] = hh; al[mf][ks] = ll;
        }
        p2 += __shfl_xor(p2, 16);
        p2 += __shfl_xor(p2, 32);
        if (lk == 0) x2s[w * 32 + mf * 16 + lr] = p2;
    }
    __syncthreads();   // c2s/comms/x2s ready (block-wide); drains stage(0) too

    // per-lane per-row state (C layout: row = lk*4 + j, col = lr)
    float x2v[2][4], sumv[2][4], minv[2][4];
    int cnv[2][4];
    #pragma unroll
    for (int mf = 0; mf < 2; ++mf)
        #pragma unroll
        for (int j = 0; j < 4; ++j) {
            int idx = w * 32 + mf * 16 + lk * 4 + j;
            x2v[mf][j] = x2s[idx];
            cnv[mf][j] = comms[idx];
            sumv[mf][j] = 0.f; minv[mf][j] = BIGF;
        }

    int buf = 0;
    for (int tt = 0; tt < NT; ++tt) {
        if (tt + 1 < NT) {
            stage(tt + 1, buf ^ 1);                     // 8 loads in flight
            asm volatile("s_waitcnt vmcnt(8)" ::: "memory");  // tile tt landed
        } else {
            asm volatile("s_waitcnt vmcnt(0)" ::: "memory");
        }
        __builtin_amdgcn_sched_barrier(0);              // rule 18: fence ds_reads

        const unsigned short* bhp = &Bst[w][buf][0][0];
        const unsigned short* blp = &Bst[w][buf][1][0];
        f32x4 ae0 = {0.f, 0.f, 0.f, 0.f}, ao0 = ae0, ae1 = ae0, ao1 = ae0;
        #pragma unroll
        for (int hf = 0; hf < 2; ++hf) {               // ks pair {2hf, 2hf+1}
            int ke = hf * 2, ko = hf * 2 + 1;
            int che = (ke * 4 + lk) ^ lr;
            int cho = (ko * 4 + lk) ^ lr;
            bf16x8 bhe = *(const bf16x8*)&bhp[(lr * 16 + che) * 8];
            bf16x8 bho = *(const bf16x8*)&bhp[(lr * 16 + cho) * 8];
            bf16x8 ble = *(const bf16x8*)&blp[(lr * 16 + che) * 8];
            bf16x8 blo = *(const bf16x8*)&blp[(lr * 16 + cho) * 8];
            ae0 = __builtin_amdgcn_mfma_f32_16x16x32_bf16(ah[0][ke], bhe, ae0, 0, 0, 0);
            ae1 = __builtin_amdgcn_mfma_f32_16x16x32_bf16(ah[1][ke], bhe, ae1, 0, 0, 0);
            ao0 = __builtin_amdgcn_mfma_f32_16x16x32_bf16(ah[0][ko], bho, ao0, 0, 0, 0);
            ao1 = __builtin_amdgcn_mfma_f32_16x16x32_bf16(ah[1][ko], bho, ao1, 0, 0, 0);
            ae0 = __builtin_amdgcn_mfma_f32_16x16x32_bf16(al[0][ke], bhe, ae0, 0, 0, 0);
            ae1 = __builtin_amdgcn_mfma_f32_16x16x32_bf16(al[1][ke], bhe, ae1, 0, 0, 0);
            ao0 = __builtin_amdgcn_mfma_f32_16x16x32_bf16(al[0][ko], bho, ao0, 0, 0, 0);
            ao1 = __builtin_amdgcn_mfma_f32_16x16x32_bf16(al[1][ko], bho, ao1, 0, 0, 0);
            ae0 = __builtin_amdgcn_mfma_f32_16x16x32_bf16(ah[0][ke], ble, ae0, 0, 0, 0);
            ae1 = __builtin_amdgcn_mfma_f32_16x16x32_bf16(ah[1][ke], ble, ae1, 0, 0, 0);
            ao0 = __builtin_amdgcn_mfma_f32_16x16x32_bf16(ah[0][ko], blo, ao0, 0, 0, 0);
            ao1 = __builtin_amdgcn_mfma_f32_16x16x32_bf16(ah[1][ko], blo, ao1, 0, 0, 0);
        }
        f32x4 acc0 = ae0 + ao0;
        f32x4 acc1 = ae1 + ao1;
        int ccol = tt * TILE_C + lr;
        float c2v = c2s[ccol];
        #pragma unroll
        for (int j = 0; j < 4; ++j) {
            float d2a = fmaf(-2.f, acc0[j], x2v[0][j] + c2v);
            float da  = __builtin_amdgcn_sqrtf(fmaxf(d2a, 0.f));
            sumv[0][j] += da;
            minv[0][j] = fminf(minv[0][j], (cnv[0][j] == ccol) ? BIGF : da);
            float d2b = fmaf(-2.f, acc1[j], x2v[1][j] + c2v);
            float db  = __builtin_amdgcn_sqrtf(fmaxf(d2b, 0.f));
            sumv[1][j] += db;
            minv[1][j] = fminf(minv[1][j], (cnv[1][j] == ccol) ? BIGF : db);
        }
        buf ^= 1;
    }

    // reduce sum/min across the 16 lr lanes sharing each node row
    #pragma unroll
    for (int mf = 0; mf < 2; ++mf)
        #pragma unroll
        for (int j = 0; j < 4; ++j) {
            float sv = sumv[mf][j], mv = minv[mf][j];
            #pragma unroll
            for (int msk = 1; msk < 16; msk <<= 1) {
                sv += __shfl_xor(sv, msk);
                mv = fminf(mv, __shfl_xor(mv, msk));
            }
            if (lr == 0) {
                int idx = w * 32 + mf * 16 + lk * 4 + j;
                sums[idx] = sv; mins[idx] = mv;
            }
        }
    __syncthreads();

    // LOO positive distance + own distance + triplet terms (2 threads per node)
    float tmean = 0.f, tminv = 0.f;
    {
        int ln = tid >> 1, half = tid & 1;
        int n = n0 + ln;
        if (n < N) {
            int cnode = comms[ln];
            float cf  = countf[cnode];
            float cm1 = fmaxf(cf - 1.f, 1.f);
            float rs  = 1.f / cm1;
            bool single = (cf == 1.f);
            const float4* srow = (const float4*)(NF + (size_t)idx0[n] * DIM) + half * 16;
            const float4* csum = (const float4*)(comm_sum + (size_t)cnode * DIM) + half * 16;
            float q = 0.f, dot = 0.f;
            #pragma unroll
            for (int m = 0; m < 16; ++m) {
                float4 sv = srow[m];
                float4 cs = csum[m];
                float4 xm = single ? make_float4(0.f, 0.f, 0.f, 0.f) : sv;
                float lx = (cs.x - xm.x) * rs - sv.x + PEPS;
                float ly = (cs.y - xm.y) * rs - sv.y + PEPS;
                float lz = (cs.z - xm.z) * rs - sv.z + PEPS;
                float lw = (cs.w - xm.w) * rs - sv.w + PEPS;
                q = fmaf(lx, lx, fmaf(ly, ly, fmaf(lz, lz, fmaf(lw, lw, q))));
                dot = fmaf(sv.x, cs.x, fmaf(sv.y, cs.y, fmaf(sv.z, cs.z, fmaf(sv.w, cs.w, dot))));
            }
            q   += __shfl_xor(q, 1);
            dot += __shfl_xor(dot, 1);
            if (half == 0) {
                float pos = sqrtf(q);
                float ownd2 = x2s[ln] + c2s[cnode] - 2.f * (dot / cf);
                float own = sqrtf(fmaxf(ownd2, 0.f));
                float mean_neg = (sums[ln] - own) * (1.f / (float)(NCOMM - 1));
                tmean = fmaxf(pos - mean_neg + ALPHA, 0.f);
                tminv = fmaxf(pos - mins[ln] + ALPHA, 0.f);
            }
        }
    }
    // block reduction of triplet sums
    #pragma unroll
    for (int msk = 1; msk < 64; msk <<= 1) {
        tmean += __shfl_xor(tmean, msk);
        tminv += __shfl_xor(tminv, msk);
    }
    if ((tid & 63) == 0) { red[w * 2] = tmean; red[w * 2 + 1] = tminv; }
    __syncthreads();
    if (tid == 0) {
        atomicAdd(&accum[0], red[0] + red[2] + red[4] + red[6]);
        atomicAdd(&accum[1], red[1] + red[3] + red[5] + red[7]);
    }
}

__global__ void k_final(const float* __restrict__ accum, float* __restrict__ out, int N) {
    if (threadIdx.x == 0) {
        out[0] = accum[0] / (float)N;
        out[1] = accum[1] / (float)N;
        out[2] = accum[2] / (float)(NCOMM * DIM);
    }
}

// ---------------- launch ----------------

extern "C" void kernel_launch(void* const* d_in, const int* in_sizes, int n_in,
                              void* d_out, int out_size, void* d_ws, size_t ws_size,
                              hipStream_t stream) {
    const float* NF  = (const float*)d_in[0];
    const int*   CBL = (const int*)d_in[1];
    int N = in_sizes[1] / 2;
    if (N <= 0) return;

    char* ws = (char*)d_ws;
    float* accum   = (float*)ws;                    // 16 B
    int*   counts  = (int*)(ws + 16);               // 2048
    int*   cursor  = (int*)(ws + 16 + 2048);
    int*   offsets = (int*)(ws + 16 + 2 * 2048);
    float* countf  = (float*)(ws + 16 + 3 * 2048);
    float* c2      = (float*)(ws + 16 + 4 * 2048);
    char* p = ws + 16 + 5 * 2048;
    int* inv    = (int*)p; p += (size_t)N * 4;
    int* comm   = (int*)p; p += (size_t)N * 4;
    int* idx0   = (int*)p; p += (size_t)N * 4;
    int* sorted = (int*)p; p += (size_t)N * 4;
    float* comm_sum = (float*)p; p += (size_t)NCOMM * DIM * 4;
    unsigned short* CMh = (unsigned short*)p; p += (size_t)NCOMM * DIM * 2;
    unsigned short* CMl = (unsigned short*)p;

    hipMemsetAsync(d_ws, 0, 16 + 2048, stream);     // accum + counts

    int nb = (N + 255) / 256;
    k_inv <<<nb, 256, 0, stream>>>(CBL, inv, N);
    k_comm<<<nb, 256, 0, stream>>>(CBL, inv, comm, idx0, counts, N);
    k_scan<<<1, NCOMM, 0, stream>>>(counts, offsets, cursor, countf);
    int nb4 = (N + 1023) / 1024;
    k_sort<<<nb4, 256, 0, stream>>>(comm, cursor, sorted, N);
    k_stats<<<NCOMM, 256, 0, stream>>>(NF, idx0, sorted, offsets, counts,
                                       comm_sum, CMh, CMl, c2, accum);
    int mb = (N + 127) / 128;
    k_main<<<mb, 256, 0, stream>>>(NF, CMh, CMl, comm_sum, c2, countf,
                                   comm, idx0, accum, N);
    k_final<<<1, 64, 0, stream>>>(accum, (float*)d_out, N);
}